// Round 13
// baseline (242.582 us; speedup 1.0000x reference)
//
#include <hip/hip_runtime.h>
#include <hip/hip_bf16.h>

#define N1 8192
#define N2 8192
#define CDIM 128
#define HC 60
#define WC 80
#define HIMG 480
#define WIMG 640
#define NPIX (HC * WC)
#define INV_DENOM (1.0f / (8192.0f * 256.0f))
#define T0KEY  0xC100u      // monotone key of bf16(8.0)
#define THIKEY 0xC200u      // monotone key of bf16(32.0)
#define SEGCAP 2048         // u32 pairs per row list (mean ~870, +40 sigma)

using bf16x8 = __attribute__((ext_vector_type(8))) short;
using f32x4  = __attribute__((ext_vector_type(4))) float;

__device__ __forceinline__ ushort f2bf(float f) {
    union { float f; unsigned u; } x; x.f = f;
    unsigned u = x.u;
    unsigned r = (u + 0x7FFFu + ((u >> 16) & 1u)) >> 16;
    return (ushort)r;
}
__device__ __forceinline__ float bf2f(unsigned bits) {
    union { unsigned u; float f; } x; x.u = bits << 16; return x.f;
}
__device__ __forceinline__ unsigned key2bits(unsigned k) {
    return k ^ ((k & 0x8000u) ? 0x8000u : 0xFFFFu);
}
__device__ __forceinline__ unsigned pair2key(unsigned x) {   // packed pair transform
    return x ^ 0x80008000u ^ (((x >> 15) & 0x00010001u) * 0x7FFFu);
}

// ---------- fp32 -> bf16 convert ----------
__global__ void cvt_kernel(const float* __restrict__ in, ushort* __restrict__ out, int n4) {
    int i = blockIdx.x * blockDim.x + threadIdx.x;
    if (i < n4) {
        float4 v = ((const float4*)in)[i];
        ushort4 o;
        o.x = f2bf(v.x); o.y = f2bf(v.y); o.z = f2bf(v.z); o.w = f2bf(v.w);
        ((ushort4*)out)[i] = o;
    }
}

// ---------- desc2 transpose, READ-coalesced ----------
// in[c][p] -> out[p][c]. Reads are lane-contiguous; scattered 4B writes land
// in the 2.4MB L2-resident output (every line eventually fully written).
// Old version read at 19.2KB lane stride (~78MB fetched for 2.4MB useful).
__global__ void tr_kernel(const float* __restrict__ in, float* __restrict__ out) {
    int e = blockIdx.x * blockDim.x + threadIdx.x;   // 614400 elements
    if (e < NPIX * CDIM) {
        int c = e / NPIX;          // magic-mul div
        int p = e - c * NPIX;
        out[(size_t)p * CDIM + c] = in[e];
    }
}

// ---------- positive term (coalesced via desc2T, plain store) ----------
__global__ void pos_kernel(const float* __restrict__ wkp1,
                           const float* __restrict__ kp1d,
                           const float* __restrict__ desc2T,
                           float* __restrict__ ploss) {
    const int i = blockIdx.x;
    const int c = threadIdx.x;            // 128 threads = 2 waves
    float y = wkp1[2 * i], x = wkp1[2 * i + 1];
    float py = fminf(fmaxf(y / (float)(HIMG - 1) * (float)(HC - 1), 0.0f), (float)(HC - 1));
    float px = fminf(fmaxf(x / (float)(WIMG - 1) * (float)(WC - 1), 0.0f), (float)(WC - 1));
    int y0 = min(max((int)floorf(py), 0), HC - 2);
    int x0 = min(max((int)floorf(px), 0), WC - 2);
    float wy = py - (float)y0;
    float wx = px - (float)x0;
    const int p00 = y0 * WC + x0;
    float v00 = desc2T[(size_t)p00 * CDIM + c];
    float v01 = desc2T[(size_t)(p00 + 1) * CDIM + c];
    float v10 = desc2T[(size_t)(p00 + WC) * CDIM + c];
    float v11 = desc2T[(size_t)(p00 + WC + 1) * CDIM + c];
    float v = v00 * (1.0f - wy) * (1.0f - wx) + v01 * (1.0f - wy) * wx
            + v10 * wy * (1.0f - wx) + v11 * wy * wx;
    float a = kp1d[(size_t)i * CDIM + c];
    float s2 = v * v, sav = a * v;
    #pragma unroll
    for (int off = 32; off >= 1; off >>= 1) {
        s2  += __shfl_down(s2, off);
        sav += __shfl_down(sav, off);
    }
    __shared__ float p2[2], pav[2];
    int wave = threadIdx.x >> 6, lane = threadIdx.x & 63;
    if (lane == 0) { p2[wave] = s2; pav[wave] = sav; }
    __syncthreads();
    if (threadIdx.x == 0) {
        float nrm = sqrtf(p2[0] + p2[1]);
        float pd = (pav[0] + pav[1]) / fmaxf(nrm, 1e-12f);
        float l = fmaxf(1.0f - pd, 0.0f) * (256.0f / 3.0f);
        ploss[i] = l * INV_DENOM;
    }
}

// ---------- masked GEMM -> bf16 dots (unchanged from R12: control) ----------
__global__ __launch_bounds__(256, 4)
void gemm_kernel(const ushort* __restrict__ A, const ushort* __restrict__ B,
                 const float* __restrict__ wkp1, const float* __restrict__ kp2,
                 ushort* __restrict__ dots, int m_off) {
    const int n0 = blockIdx.x * 128;
    const int m0 = m_off + blockIdx.y * 128;
    const int lane = threadIdx.x & 63;
    const int wave = threadIdx.x >> 6;
    const int wm = wave >> 1, wn = wave & 1;
    const int lrow = lane & 15, quad = lane >> 4;

    __shared__ float s_w[256];    // wkp1[m0..m0+128) pairs
    __shared__ float s_k[256];    // kp2 [n0..n0+128) pairs
    s_w[threadIdx.x] = wkp1[2 * m0 + threadIdx.x];
    s_k[threadIdx.x] = kp2[2 * n0 + threadIdx.x];
    __syncthreads();

    f32x4 acc[4][4];
    #pragma unroll
    for (int i = 0; i < 4; i++)
        #pragma unroll
        for (int j = 0; j < 4; j++) acc[i][j] = (f32x4){0.f, 0.f, 0.f, 0.f};

    const int mbase = m0 + wm * 64 + lrow;
    const int nbase = n0 + wn * 64 + lrow;
    #pragma unroll
    for (int kit = 0; kit < 4; kit++) {
        const int kk = kit * 32 + quad * 8;
        bf16x8 af[4], bfr[4];
        #pragma unroll
        for (int t = 0; t < 4; t++) {
            af[t]  = *(const bf16x8*)(A + (size_t)(mbase + t * 16) * CDIM + kk);
            bfr[t] = *(const bf16x8*)(B + (size_t)(nbase + t * 16) * CDIM + kk);
        }
        #pragma unroll
        for (int mt = 0; mt < 4; mt++)
            #pragma unroll
            for (int nt = 0; nt < 4; nt++)
                acc[mt][nt] = __builtin_amdgcn_mfma_f32_16x16x32_bf16(
                    af[mt], bfr[nt], acc[mt][nt], 0, 0, 0);
    }

    float ky[4], kx[4];
    #pragma unroll
    for (int nt = 0; nt < 4; nt++) {
        int jl = wn * 64 + nt * 16 + lrow;
        ky[nt] = s_k[2 * jl]; kx[nt] = s_k[2 * jl + 1];
    }

    const float thr = 2.0f * sqrtf(32.0f) + 0.1f;
    const float thr2 = thr * thr;
    const size_t colbase = (size_t)(n0 + wn * 64 + lrow * 4);
    #pragma unroll
    for (int mt = 0; mt < 4; mt++) {
        #pragma unroll
        for (int r = 0; r < 4; r++) {
            const int il = wm * 64 + mt * 16 + quad * 4 + r;      // local row
            const int i = m0 + il;
            const float wy = s_w[2 * il], wx = s_w[2 * il + 1];
            unsigned h[4];
            #pragma unroll
            for (int nt = 0; nt < 4; nt++) {
                float dy = wy - ky[nt], dx = wx - kx[nt];
                float v = acc[mt][nt][r];
                if (dy * dy + dx * dx <= thr2) v -= 5.0f;
                h[nt] = (unsigned)f2bf(v);
            }
            unsigned long long pk = (unsigned long long)(h[0] | (h[1] << 16))
                                  | ((unsigned long long)(h[2] | (h[3] << 16)) << 32);
            *(unsigned long long*)(dots + (size_t)(i - m_off) * N2 + colbase) = pk;
        }
    }
}

// ---------- per-row top-256 hinge sum: WAVE per row, scan compaction ----------
// R12 post-mortem: R10's pass-1 was a 16-step serially-dependent
// ballot->mbcnt->store->base chain. Replacement has NO cross-lane serial
// chain: pass A counts per lane (pure VALU), one 6-step shuffle exclusive
// scan, pass B re-reads (L1/L2-hot) and writes each lane's pairs at its
// private offset (within-lane dependency only). Zero barriers, zero ballots.
// Bracket checks exact as before; never-taken fallback bisects from global.
__global__ __launch_bounds__(256)
void select_kernel(const ushort* __restrict__ dots, float* __restrict__ rloss,
                   int m_off) {
    const int wave = threadIdx.x >> 6;
    const int lane = threadIdx.x & 63;
    const int row = blockIdx.x * 4 + wave;

    __shared__ unsigned seg[4][SEGCAP];    // 32 KB
    unsigned* lst = seg[wave];

    const uint4* rp4 = (const uint4*)(dots + (size_t)row * N2);  // 1024 uint4
    const unsigned T0HI  = (T0KEY << 16) | 0xFFFFu;
    const unsigned THIHI = (THIKEY << 16) | 0xFFFFu;

    // ---- pass A: per-lane counts (no cross-lane ops)
    int myc = 0;       // pairs with >=1 half > T0 (u32 slots this lane needs)
    int clh = 0;       // halves > T0
    int chh = 0;       // halves > THI
    #pragma unroll
    for (int j = 0; j < 16; j++) {
        uint4 w = rp4[lane + 64 * j];
        unsigned xs[4] = {w.x, w.y, w.z, w.w};
        #pragma unroll
        for (int u = 0; u < 4; u++) {
            unsigned kk = pair2key(xs[u]);
            unsigned lowk = kk & 0xFFFFu;
            int ql = (int)(lowk > T0KEY), qh = (int)(kk > T0HI);
            clh += ql + qh;
            chh += (int)(lowk > THIKEY) + (int)(kk > THIHI);
            myc += (ql | qh);
        }
    }
    // exclusive scan of myc; also reduce clh/chh
    int inc = myc, rl = clh, rh = chh;
    #pragma unroll
    for (int off = 1; off < 64; off <<= 1) {
        int t = __shfl_up(inc, off);
        if (lane >= off) inc += t;
        rl += __shfl_down(rl, off);     // tree reduce (valid at lane 0)
        rh += __shfl_down(rh, off);
    }
    const int mybase = inc - myc;
    const int len = __shfl(inc, 63);            // total u32 pairs
    const int totLow = __shfl(rl, 0);
    const int totHi  = __shfl(rh, 0);
    const bool ok = (totLow >= 256) && (totHi <= 255) && (len <= SEGCAP);

    unsigned kt;          // key of 256th-largest (attained)
    float s = 0.f; int cgt = 0;

    if (ok) {
        // ---- pass B: re-read (cache-hot), write own candidates at own offset
        int ofs = mybase;
        #pragma unroll
        for (int j = 0; j < 16; j++) {
            uint4 w = rp4[lane + 64 * j];
            unsigned xs[4] = {w.x, w.y, w.z, w.w};
            #pragma unroll
            for (int u = 0; u < 4; u++) {
                unsigned kk = pair2key(xs[u]);
                if ((kk & 0xFFFFu) > T0KEY || kk > T0HI) lst[ofs++] = kk;
            }
        }
        // ---- bisect the list over [T0, THI]
        int lo = (int)T0KEY, hi = (int)THIKEY;
        while (hi - lo > 1) {
            unsigned midu = (unsigned)((lo + hi) >> 1);
            unsigned midhi = (midu << 16) | 0xFFFFu;
            int c = 0;
            for (int p = lane; p < len; p += 64) {
                unsigned x = lst[p];
                c += (int)((x & 0xFFFFu) > midu) + (int)(x > midhi);
            }
            #pragma unroll
            for (int off = 32; off >= 1; off >>= 1) c += __shfl_down(c, off);
            c = __shfl(c, 0);
            if (c >= 256) lo = (int)midu; else hi = (int)midu;
        }
        kt = (unsigned)hi;
        const unsigned kthi = (kt << 16) | 0xFFFFu;
        for (int p = lane; p < len; p += 64) {
            unsigned x = lst[p];
            unsigned lowk = x & 0xFFFFu, highk = x >> 16;
            if (lowk > kt) { s += bf2f(key2bits(lowk))  - 0.2f; cgt++; }
            if (x > kthi)  { s += bf2f(key2bits(highk)) - 0.2f; cgt++; }
        }
    } else {
        // ---- exact fallback (>40-sigma rare): bisect full range from global
        int lo = -1, hi = 65535;
        while (hi - lo > 1) {
            unsigned midu = (unsigned)((lo + hi) >> 1);
            unsigned midhi = (midu << 16) | 0xFFFFu;
            int c = 0;
            for (int j = 0; j < 16; j++) {
                uint4 w = rp4[lane + 64 * j];
                unsigned xs[4] = {w.x, w.y, w.z, w.w};
                #pragma unroll
                for (int u = 0; u < 4; u++) {
                    unsigned kk = pair2key(xs[u]);
                    c += (int)((kk & 0xFFFFu) > midu) + (int)(kk > midhi);
                }
            }
            #pragma unroll
            for (int off = 32; off >= 1; off >>= 1) c += __shfl_down(c, off);
            c = __shfl(c, 0);
            if (c >= 256) lo = (int)midu; else hi = (int)midu;
        }
        kt = (unsigned)hi;
        const unsigned kthi = (kt << 16) | 0xFFFFu;
        for (int j = 0; j < 16; j++) {
            uint4 w = rp4[lane + 64 * j];
            unsigned xs[4] = {w.x, w.y, w.z, w.w};
            #pragma unroll
            for (int u = 0; u < 4; u++) {
                unsigned kk = pair2key(xs[u]);
                unsigned lowk = kk & 0xFFFFu, highk = kk >> 16;
                if (lowk > kt) { s += fmaxf(bf2f(key2bits(lowk))  - 0.2f, 0.f); cgt++; }
                if (kk > kthi) { s += fmaxf(bf2f(key2bits(highk)) - 0.2f, 0.f); cgt++; }
            }
        }
    }

    #pragma unroll
    for (int off = 32; off >= 1; off >>= 1) {
        s += __shfl_down(s, off);
        cgt += __shfl_down(cgt, off);
    }
    if (lane == 0) {
        float vt = bf2f(key2bits(kt));
        float S = s + (float)(256 - cgt) * fmaxf(vt - 0.2f, 0.0f);
        rloss[m_off + row] = S * INV_DENOM;
    }
}

// ---------- final reduce: sum 2*N1 floats -> out[0] ----------
__global__ void reduce_kernel(const float* __restrict__ a, float* __restrict__ out) {
    const int t = threadIdx.x;
    float s = 0.f;
    for (int i = t; i < 2 * N1; i += 256) s += a[i];
    #pragma unroll
    for (int off = 32; off >= 1; off >>= 1) s += __shfl_down(s, off);
    __shared__ float ws[4];
    int wave = t >> 6, lane = t & 63;
    if (lane == 0) ws[wave] = s;
    __syncthreads();
    if (t == 0) out[0] = ws[0] + ws[1] + ws[2] + ws[3];
}

extern "C" void kernel_launch(void* const* d_in, const int* in_sizes, int n_in,
                              void* d_out, int out_size, void* d_ws, size_t ws_size,
                              hipStream_t stream) {
    const float* wkp1  = (const float*)d_in[1];
    const float* kp2   = (const float*)d_in[2];
    const float* kp1d  = (const float*)d_in[3];
    const float* kp2d  = (const float*)d_in[4];
    const float* desc2 = (const float*)d_in[5];
    float* out = (float*)d_out;

    ushort* Abf   = (ushort*)d_ws;                         // 2 MB
    ushort* Bbf   = Abf + (size_t)N1 * CDIM;               // 2 MB
    float*  loss  = (float*)(Bbf + (size_t)N2 * CDIM);     // 64 KB (pos then rows)
    float*  d2T   = loss + 2 * N1;                         // 2.4 MB transposed desc2
    ushort* dots  = (ushort*)(d2T + (size_t)NPIX * CDIM);  // chunked dots

    size_t head_bytes = (size_t)(N1 + N2) * CDIM * sizeof(ushort)
                      + 2 * N1 * sizeof(float)
                      + (size_t)NPIX * CDIM * sizeof(float);
    size_t avail = (ws_size > head_bytes) ? (ws_size - head_bytes) : 0;
    long rows_chunk = (long)(avail / ((size_t)N2 * sizeof(ushort)));
    rows_chunk = (rows_chunk / 128) * 128;
    if (rows_chunk > N1) rows_chunk = N1;
    if (rows_chunk < 128) rows_chunk = 128;      // requires ws >= ~9 MB

    int n4 = N1 * CDIM / 4;
    cvt_kernel<<<(n4 + 255) / 256, 256, 0, stream>>>(kp1d, Abf, n4);
    cvt_kernel<<<(n4 + 255) / 256, 256, 0, stream>>>(kp2d, Bbf, n4);
    tr_kernel<<<(NPIX * CDIM + 255) / 256, 256, 0, stream>>>(desc2, d2T);

    pos_kernel<<<N1, 128, 0, stream>>>(wkp1, kp1d, d2T, loss);

    for (int r0 = 0; r0 < N1; r0 += (int)rows_chunk) {
        int rows = (int)((N1 - r0 < rows_chunk) ? (N1 - r0) : rows_chunk);
        dim3 grid(N2 / 128, rows / 128);
        gemm_kernel<<<grid, 256, 0, stream>>>(Abf, Bbf, wkp1, kp2, dots, r0);
        select_kernel<<<rows / 4, 256, 0, stream>>>(dots, loss + N1, r0);
    }

    reduce_kernel<<<1, 256, 0, stream>>>(loss, out);
}